// Round 6
// baseline (133.111 us; speedup 1.0000x reference)
//
#include <hip/hip_runtime.h>

// DotProductAttention reduced form (verified rounds 1-8, absmax 0.0156):
//   Qeff[q] = 0.7*Q[q-1] + Q[q] + 0.7*Q[q+1]  (zero pad at edges)
//   out[q]  = softmax_{k <= max(q-1,0)}( Qeff[q]·K[k]/8 + beta[k] ) @ V
// Round 14 (resubmit; round-15 bench was an infra failure): allocator ignores
// waves_per_eu (r13: VGPR stuck 84 at 256-thr); empirically 512-thr blocks get
// a 4-wave/EU target (128 VGPR, r10). So: use the verified round-9 structure
// (8 waves = kh x par x qh, 32q x 32k per wave) but (a) one 64-row q-tile per
// block, grid 512 -> 2 blocks/CU = 4 waves/SIMD, odd/even j-map so co-resident
// pairs sum to 33 tiles; (b) per-wave demand cut to ~120 <= 128: K-frags only
// are double-buffered, V-frags loaded at comp start (consumed ~250cy later at
// PV, covers L2), beta exp-scaled in LDS. __launch_bounds__(512,4) pins the
// 128 budget. LDS 44KB = slab[2][64][72] + bl[2048]. Epilogue: 2-barrier
// 4-way (kh x par) combine (round-9 scheme). Frag store F[hd][tile][frag]
// [lane][8] by cvt8 (unchanged). Permuted key->M-row keeps S^T C-frag == PV
// B-frag. Fixed-max softmax, runtime dm.

typedef short bf16x8 __attribute__((ext_vector_type(8)));
typedef float f32x4  __attribute__((ext_vector_type(4)));

constexpr int S_ = 2048;
constexpr int D_ = 64;
constexpr float LOG2E = 1.44269504088896341f;
constexpr float KSC = 0.125f * LOG2E;   // 1/sqrt(64), log2 domain

template <bool B> struct BC { static constexpr bool v = B; };

// pack two fp32 -> dword of 2 bf16 (round-half-up), lo in low 16
__device__ __forceinline__ unsigned pk2(float lo, float hi) {
    union { float f; unsigned u; } a, b;
    a.f = lo; b.f = hi;
    return __builtin_amdgcn_perm(b.u + 0x8000u, a.u + 0x8000u, 0x07060302u);
}

// ---- fragment pre-swizzle: F[hd][tile][frag][lane][8] bf16 ----
// frag 0..7  = K A-frags  (kh*4 + mb*2 + hh): lane(n,qd) holds
//              K[key = 64t + 32kh + 8(n>>2) + (n&3) + 4mb][d = 32hh + 8qd .. +8]
// frag 8..15 = V^T A-frags (8 + kh*4 + mb): lane(n,qd) holds
//              V[key = 64t + 32kh + 8qd + j][d = 16mb + n], j = 0..7
__global__ __launch_bounds__(256)
void cvt8(const float* __restrict__ K, const float* __restrict__ V,
          unsigned short* __restrict__ F)
{
    __shared__ float T[64][68];   // V^T fp32: [d][key]

    const int bid = blockIdx.x;            // 512: hd = bid&15 -> XCD bid%8 (matches attn)
    const int hd = bid & 15, tt = bid >> 4;
    const float* Kt = K + ((size_t)hd * S_ + tt * 64) * D_;
    const float* Vt = V + ((size_t)hd * S_ + tt * 64) * D_;
    unsigned short* Ft = F + (size_t)(hd * 32 + tt) * 8192;

    const int t = threadIdx.x;
    const int key = t >> 2, d0 = (t & 3) << 4;

    // ---- V: coalesced read -> transposed LDS ----
    {
        const float* vp = Vt + key * D_ + d0;
        #pragma unroll
        for (int i = 0; i < 4; ++i) {
            float4 v4 = *(const float4*)(vp + 4 * i);
            T[d0 + 4 * i + 0][key] = v4.x;
            T[d0 + 4 * i + 1][key] = v4.y;
            T[d0 + 4 * i + 2][key] = v4.z;
            T[d0 + 4 * i + 3][key] = v4.w;
        }
    }

    // ---- K: coalesced read -> direct frag write ----
    {
        const float* kp = Kt + key * D_ + d0;
        float4 a = *(const float4*)(kp);
        float4 b = *(const float4*)(kp + 4);
        float4 c = *(const float4*)(kp + 8);
        float4 d = *(const float4*)(kp + 12);
        uint4 w0 = make_uint4(pk2(a.x, a.y), pk2(a.z, a.w), pk2(b.x, b.y), pk2(b.z, b.w));
        uint4 w1 = make_uint4(pk2(c.x, c.y), pk2(c.z, c.w), pk2(d.x, d.y), pk2(d.z, d.w));
        const int r5 = key & 31;
        const int kh = key >> 5, mb = (r5 >> 2) & 1;
        const int n = ((r5 >> 3) << 2) | (r5 & 3);       // inverse key->M-row perm
        const int hh = d0 >> 5, qd0 = (d0 >> 3) & 3;
        const int f0 = (kh << 2) | (mb << 1) | hh;
        *(uint4*)(Ft + f0 * 512 + ((qd0 << 4) | n) * 8)       = w0;
        *(uint4*)(Ft + f0 * 512 + (((qd0 + 1) << 4) | n) * 8) = w1;
    }
    __syncthreads();

    // ---- V frag emission: contiguous LDS reads, coalesced 16B writes ----
    #pragma unroll
    for (int s = 0; s < 2; ++s) {
        const int slot = t + s * 256;
        const int fr = slot >> 6, lane = slot & 63;
        const int kh = fr >> 2, mb = fr & 3, n = lane & 15, qd = lane >> 4;
        const float* row = &T[mb * 16 + n][kh * 32 + qd * 8];
        uint4 w = make_uint4(pk2(row[0], row[1]), pk2(row[2], row[3]),
                             pk2(row[4], row[5]), pk2(row[6], row[7]));
        *(uint4*)(Ft + (8 + fr) * 512 + lane * 8) = w;
    }
}

__global__ __launch_bounds__(512, 4)
void attn14(const float* __restrict__ Q, const float* __restrict__ beta,
            const unsigned short* __restrict__ F, float* __restrict__ out)
{
    __shared__ float slab[2][64][72];   // [kh][row][0..63: O, 64: l]
    __shared__ float bl[S_];            // exp-scaled beta (log2 domain)

    const int bid = blockIdx.x;
    const int hd = bid & 15;            // head pinned to XCD bid&7 (2 heads/XCD)
    const int rest = bid >> 4;          // 0..31
    // odd/even map: co-resident pair (bid, bid+256) gets j1+j2 = 31 (33 tiles)
    const int j = (rest < 16) ? (31 - 2 * rest) : (2 * (rest - 16));

    const int q0 = j << 6;
    const int nt = j + 1;

    const float* Qh = Q + (size_t)hd * S_ * D_;
    const unsigned short* Fh = F + (size_t)hd * 32 * 8192;

    const int t = threadIdx.x, lane = t & 63;
    const int wv = t >> 6;
    const int kh = wv & 1, par = (wv >> 1) & 1, qh = wv >> 2;
    const int n_l = lane & 15, qd = lane >> 4;
    const int qbase = q0 + (qh << 5);

    // ---- stage beta*log2e in LDS once (read broadcast by all waves/tiles) ----
    #pragma unroll
    for (int i = 0; i < 4; ++i) bl[t + i * 512] = beta[t + i * 512] * LOG2E;
    __syncthreads();

    // fragment offsets (ushort) within one tile's 8192-ushort block
    const int lo = lane * 8;
    int kfo[2][2], vfo[4];
    #pragma unroll
    for (int mb = 0; mb < 2; ++mb)
        #pragma unroll
        for (int hh = 0; hh < 2; ++hh)
            kfo[mb][hh] = ((kh << 2) | (mb << 1) | hh) * 512 + lo;
    #pragma unroll
    for (int mb = 0; mb < 4; ++mb)
        vfo[mb] = (8 + (kh << 2) + mb) * 512 + lo;

    const int kvo = (kh << 5) + (qd << 3);   // lane's key offset within a tile

    auto ld_ka = [&](int tile, bf16x8 (&ka)[2][2]) {
        const unsigned short* fp = Fh + (size_t)tile * 8192;
        ka[0][0] = *(const bf16x8*)(fp + kfo[0][0]);
        ka[0][1] = *(const bf16x8*)(fp + kfo[0][1]);
        ka[1][0] = *(const bf16x8*)(fp + kfo[1][0]);
        ka[1][1] = *(const bf16x8*)(fp + kfo[1][1]);
    };

    // ---- Qeff B-fragments from global fp32 Q (two q-rows per lane) ----
    bf16x8 qb[2][2];
    #pragma unroll
    for (int ng = 0; ng < 2; ++ng) {
        const int q = qbase + (ng << 4) + n_l;
        const float wp = (q > 0) ? 0.7f : 0.0f;
        const float wn = (q + 1 < S_) ? 0.7f : 0.0f;
        const float* qc = Qh + (size_t)q * D_;
        const float* qpp = qc - ((q > 0) ? D_ : 0);
        const float* qnn = qc + ((q + 1 < S_) ? D_ : 0);
        #pragma unroll
        for (int hh = 0; hh < 2; ++hh) {
            const int d0 = (hh << 5) + (qd << 3);
            float4 c0 = *(const float4*)(qc + d0),  c1 = *(const float4*)(qc + d0 + 4);
            float4 p0 = *(const float4*)(qpp + d0), p1 = *(const float4*)(qpp + d0 + 4);
            float4 n0 = *(const float4*)(qnn + d0), n1 = *(const float4*)(qnn + d0 + 4);
            float e0 = fmaf(wn, n0.x, fmaf(wp, p0.x, c0.x));
            float e1 = fmaf(wn, n0.y, fmaf(wp, p0.y, c0.y));
            float e2 = fmaf(wn, n0.z, fmaf(wp, p0.z, c0.z));
            float e3 = fmaf(wn, n0.w, fmaf(wp, p0.w, c0.w));
            float e4 = fmaf(wn, n1.x, fmaf(wp, p1.x, c1.x));
            float e5 = fmaf(wn, n1.y, fmaf(wp, p1.y, c1.y));
            float e6 = fmaf(wn, n1.z, fmaf(wp, p1.z, c1.z));
            float e7 = fmaf(wn, n1.w, fmaf(wp, p1.w, c1.w));
            union { unsigned u[4]; bf16x8 v; } qu;
            qu.u[0] = pk2(e0, e1); qu.u[1] = pk2(e2, e3);
            qu.u[2] = pk2(e4, e5); qu.u[3] = pk2(e6, e7);
            qb[ng][hh] = qu.v;
        }
    }

    f32x4 o[4][2];
    float l[2] = {0.0f, 0.0f};
    #pragma unroll
    for (int mb = 0; mb < 4; ++mb)
        #pragma unroll
        for (int ng = 0; ng < 2; ++ng) o[mb][ng] = (f32x4){0, 0, 0, 0};

    // comp: V-frags + beta issued first (consumed at PV/softmax later, latency
    // covered by S-MFMAs); ka for tile+2 prefetched mid-body if PRE.
    auto comp = [&](int tile, bf16x8 (&kaC)[2][2], bf16x8 (&kaN)[2][2], auto prc) {
        constexpr bool PRE = decltype(prc)::v;
        const int kb = (tile << 6) + kvo;
        const unsigned short* fp = Fh + (size_t)tile * 8192;
        bf16x8 vb[4];
        #pragma unroll
        for (int mb = 0; mb < 4; ++mb)
            vb[mb] = *(const bf16x8*)(fp + vfo[mb]);
        float4 b0 = *(const float4*)&bl[kb];
        float4 b1 = *(const float4*)&bl[kb + 4];
        const float bt[8] = {b0.x, b0.y, b0.z, b0.w, b1.x, b1.y, b1.z, b1.w};
        const f32x4 zz = {0, 0, 0, 0};
        f32x4 acc[2][2];
        #pragma unroll
        for (int mb = 0; mb < 2; ++mb)
            #pragma unroll
            for (int ng = 0; ng < 2; ++ng) {
                f32x4 a = __builtin_amdgcn_mfma_f32_16x16x32_bf16(kaC[mb][0], qb[ng][0], zz, 0, 0, 0);
                acc[mb][ng] = __builtin_amdgcn_mfma_f32_16x16x32_bf16(kaC[mb][1], qb[ng][1], a, 0, 0, 0);
            }
        if constexpr (PRE) ld_ka(tile + 2, kaN);
        const bool dm = (tile == nt - 1);
        #pragma unroll
        for (int ng = 0; ng < 2; ++ng) {
            const int qr = qbase + (ng << 4) + n_l;
            float pv[8];
            float la = 0.0f;
            #pragma unroll
            for (int jj = 0; jj < 8; ++jj) {
                const int mb = jj >> 2, r = jj & 3;
                float sv = fmaf(acc[mb][ng][r], KSC, bt[jj]);
                if (dm) {
                    const int key = kb + jj;
                    if (!((key < qr) || (qr == 0 && key == 0))) sv = -1.0e30f;
                }
                pv[jj] = __builtin_amdgcn_exp2f(sv);
                la += pv[jj];
            }
            l[ng] += la;
            union { unsigned u[4]; bf16x8 v; } pf;
            pf.u[0] = pk2(pv[0], pv[1]);
            pf.u[1] = pk2(pv[2], pv[3]);
            pf.u[2] = pk2(pv[4], pv[5]);
            pf.u[3] = pk2(pv[6], pv[7]);
            #pragma unroll
            for (int mb = 0; mb < 4; ++mb)
                o[mb][ng] = __builtin_amdgcn_mfma_f32_16x16x32_bf16(vb[mb], pf.v, o[mb][ng], 0, 0, 0);
        }
    };

    // ---- barrier-free K-loop, ka 1-deep ping-pong prefetch ----
    bf16x8 kaA[2][2], kaB[2][2];
    int it = par;
    if (it < nt) {
        ld_ka(it, kaA);
        while (it + 4 < nt) {
            comp(it,     kaA, kaB, BC<true>{});
            comp(it + 2, kaB, kaA, BC<true>{});
            it += 4;
        }
        if (it + 2 < nt) {
            comp(it,     kaA, kaB, BC<true>{});
            comp(it + 2, kaB, kaA, BC<false>{});
        } else {
            comp(it, kaA, kaB, BC<false>{});
        }
    }

    // ---- epilogue: quad-reduce l, 2-barrier 4-way (kh x par) combine ----
    #pragma unroll
    for (int ng = 0; ng < 2; ++ng) {
        l[ng] += __shfl_xor(l[ng], 16);
        l[ng] += __shfl_xor(l[ng], 32);
    }
    if (par == 1) {
        #pragma unroll
        for (int ng = 0; ng < 2; ++ng) {
            const int row = (qh << 5) + (ng << 4) + n_l;
            #pragma unroll
            for (int mb = 0; mb < 4; ++mb)
                *(float4*)&slab[kh][row][(mb << 4) + (qd << 2)] =
                    make_float4(o[mb][ng][0], o[mb][ng][1], o[mb][ng][2], o[mb][ng][3]);
            if (qd == 0) slab[kh][row][64] = l[ng];
        }
    }
    __syncthreads();
    if (par == 0) {
        #pragma unroll
        for (int ng = 0; ng < 2; ++ng) {
            const int row = (qh << 5) + (ng << 4) + n_l;
            #pragma unroll
            for (int mb = 0; mb < 4; ++mb) {
                float4 pv4 = *(float4*)&slab[kh][row][(mb << 4) + (qd << 2)];
                o[mb][ng][0] += pv4.x; o[mb][ng][1] += pv4.y;
                o[mb][ng][2] += pv4.z; o[mb][ng][3] += pv4.w;
            }
            l[ng] += slab[kh][row][64];
            if (kh == 0) {   // publish kh0 totals (same wave read-then-write, in order)
                #pragma unroll
                for (int mb = 0; mb < 4; ++mb)
                    *(float4*)&slab[0][row][(mb << 4) + (qd << 2)] =
                        make_float4(o[mb][ng][0], o[mb][ng][1], o[mb][ng][2], o[mb][ng][3]);
                if (qd == 0) slab[0][row][64] = l[ng];
            }
        }
    }
    __syncthreads();
    if (par == 0 && kh == 1) {
        #pragma unroll
        for (int ng = 0; ng < 2; ++ng) {
            const int row = (qh << 5) + (ng << 4) + n_l;
            const float inv = 1.0f / (l[ng] + slab[0][row][64]);
            float* op = out + ((size_t)hd * S_ + q0 + row) * D_ + (qd << 2);
            #pragma unroll
            for (int mb = 0; mb < 4; ++mb) {
                float4 pv4 = *(float4*)&slab[0][row][(mb << 4) + (qd << 2)];
                *(float4*)(op + (mb << 4)) =
                    make_float4((o[mb][ng][0] + pv4.x) * inv, (o[mb][ng][1] + pv4.y) * inv,
                                (o[mb][ng][2] + pv4.z) * inv, (o[mb][ng][3] + pv4.w) * inv);
            }
        }
    }
}

extern "C" void kernel_launch(void* const* d_in, const int* in_sizes, int n_in,
                              void* d_out, int out_size, void* d_ws, size_t ws_size,
                              hipStream_t stream) {
    const float* Q    = (const float*)d_in[0];
    const float* K    = (const float*)d_in[1];
    const float* V    = (const float*)d_in[2];
    const float* beta = (const float*)d_in[3];
    // d_in[4]: causal mask (deterministic triu) — handled analytically in-kernel.
    float* out = (float*)d_out;

    unsigned short* F = (unsigned short*)d_ws;   // 16 hd x 32 t x 16 frag x 512 = 8 MB

    cvt8<<<dim3(512), 256, 0, stream>>>(K, V, F);
    attn14<<<dim3(512), 512, 0, stream>>>(Q, beta, F, out);
}

// Round 7
// 113.872 us; speedup vs baseline: 1.1690x; 1.1690x over previous
//
#include <hip/hip_runtime.h>

// DotProductAttention reduced form (verified rounds 1-8, absmax 0.0156):
//   Qeff[q] = 0.7*Q[q-1] + Q[q] + 0.7*Q[q+1]  (zero pad at edges)
//   out[q]  = softmax_{k <= max(q-1,0)}( Qeff[q]·K[k]/8 + beta[k] ) @ V
// Round 16: root-cause theory for ALL prior rounds' anomaly (VGPR_Count low
// 64-128 yet 21-88MB scratch traffic, MfmaUtil ~6%): the frag buffers were
// passed BY REFERENCE into the ld/comp lambdas -> address escapes -> SROA
// fails -> ka/vb dbuf lives in SCRATCH, every MFMA operand is a scratch
// reload. Fix: identical attn9 schedule (grid 256 = hd x pr, p-loop over
// (pr, 31-pr), 8 waves kh x par x qh, 32q x 32k per wave, full ka+vb
// ping-pong dbuf, 3-barrier 4-way combine) but ld/comp are MACROS operating
// on plain locals (no escape), and beta is exp-scaled once into LDS
// (strictly cheaper than per-tile global loads; drops bt from dbuf state,
// true demand ~135 <= budget). Falsifiable: VGPR should jump >128 and
// WRITE_SIZE collapse to ~8.5MB. Frag store F[hd][tile][frag][lane][8] by
// cvt8 (unchanged). Permuted key->M-row keeps S^T C-frag == PV B-frag.

typedef short bf16x8 __attribute__((ext_vector_type(8)));
typedef float f32x4  __attribute__((ext_vector_type(4)));

constexpr int S_ = 2048;
constexpr int D_ = 64;
constexpr float LOG2E = 1.44269504088896341f;
constexpr float KSC = 0.125f * LOG2E;   // 1/sqrt(64), log2 domain

// pack two fp32 -> dword of 2 bf16 (round-half-up), lo in low 16
__device__ __forceinline__ unsigned pk2(float lo, float hi) {
    union { float f; unsigned u; } a, b;
    a.f = lo; b.f = hi;
    return __builtin_amdgcn_perm(b.u + 0x8000u, a.u + 0x8000u, 0x07060302u);
}

// ---- fragment pre-swizzle: F[hd][tile][frag][lane][8] bf16 ----
// frag 0..7  = K A-frags  (kh*4 + mb*2 + hh): lane(n,qd) holds
//              K[key = 64t + 32kh + 8(n>>2) + (n&3) + 4mb][d = 32hh + 8qd .. +8]
// frag 8..15 = V^T A-frags (8 + kh*4 + mb): lane(n,qd) holds
//              V[key = 64t + 32kh + 8qd + j][d = 16mb + n], j = 0..7
__global__ __launch_bounds__(256)
void cvt8(const float* __restrict__ K, const float* __restrict__ V,
          unsigned short* __restrict__ F)
{
    __shared__ float T[64][68];   // V^T fp32: [d][key]

    const int bid = blockIdx.x;            // 512: hd = bid&15 -> XCD bid%8 (matches attn)
    const int hd = bid & 15, tt = bid >> 4;
    const float* Kt = K + ((size_t)hd * S_ + tt * 64) * D_;
    const float* Vt = V + ((size_t)hd * S_ + tt * 64) * D_;
    unsigned short* Ft = F + (size_t)(hd * 32 + tt) * 8192;

    const int t = threadIdx.x;
    const int key = t >> 2, d0 = (t & 3) << 4;

    // ---- V: coalesced read -> transposed LDS ----
    {
        const float* vp = Vt + key * D_ + d0;
        #pragma unroll
        for (int i = 0; i < 4; ++i) {
            float4 v4 = *(const float4*)(vp + 4 * i);
            T[d0 + 4 * i + 0][key] = v4.x;
            T[d0 + 4 * i + 1][key] = v4.y;
            T[d0 + 4 * i + 2][key] = v4.z;
            T[d0 + 4 * i + 3][key] = v4.w;
        }
    }

    // ---- K: coalesced read -> direct frag write ----
    {
        const float* kp = Kt + key * D_ + d0;
        float4 a = *(const float4*)(kp);
        float4 b = *(const float4*)(kp + 4);
        float4 c = *(const float4*)(kp + 8);
        float4 d = *(const float4*)(kp + 12);
        uint4 w0 = make_uint4(pk2(a.x, a.y), pk2(a.z, a.w), pk2(b.x, b.y), pk2(b.z, b.w));
        uint4 w1 = make_uint4(pk2(c.x, c.y), pk2(c.z, c.w), pk2(d.x, d.y), pk2(d.z, d.w));
        const int r5 = key & 31;
        const int kh = key >> 5, mb = (r5 >> 2) & 1;
        const int n = ((r5 >> 3) << 2) | (r5 & 3);       // inverse key->M-row perm
        const int hh = d0 >> 5, qd0 = (d0 >> 3) & 3;
        const int f0 = (kh << 2) | (mb << 1) | hh;
        *(uint4*)(Ft + f0 * 512 + ((qd0 << 4) | n) * 8)       = w0;
        *(uint4*)(Ft + f0 * 512 + (((qd0 + 1) << 4) | n) * 8) = w1;
    }
    __syncthreads();

    // ---- V frag emission: contiguous LDS reads, coalesced 16B writes ----
    #pragma unroll
    for (int s = 0; s < 2; ++s) {
        const int slot = t + s * 256;
        const int fr = slot >> 6, lane = slot & 63;
        const int kh = fr >> 2, mb = fr & 3, n = lane & 15, qd = lane >> 4;
        const float* row = &T[mb * 16 + n][kh * 32 + qd * 8];
        uint4 w = make_uint4(pk2(row[0], row[1]), pk2(row[2], row[3]),
                             pk2(row[4], row[5]), pk2(row[6], row[7]));
        *(uint4*)(Ft + (8 + fr) * 512 + lane * 8) = w;
    }
}

// ---- macro (not lambda!) tile load/compute: plain-local access, no escape ----
#define LD_T(TILE, KA, VB) do {                                              \
    const unsigned short* fp_ = Fh + (size_t)(TILE) * 8192;                  \
    KA[0][0] = *(const bf16x8*)(fp_ + kfo[0][0]);                            \
    KA[0][1] = *(const bf16x8*)(fp_ + kfo[0][1]);                            \
    KA[1][0] = *(const bf16x8*)(fp_ + kfo[1][0]);                            \
    KA[1][1] = *(const bf16x8*)(fp_ + kfo[1][1]);                            \
    VB[0] = *(const bf16x8*)(fp_ + vfo[0]);                                  \
    VB[1] = *(const bf16x8*)(fp_ + vfo[1]);                                  \
    VB[2] = *(const bf16x8*)(fp_ + vfo[2]);                                  \
    VB[3] = *(const bf16x8*)(fp_ + vfo[3]);                                  \
} while (0)

#define COMP_T(TILE, KA, VB) do {                                            \
    const int kb_ = ((TILE) << 6) + kvo;                                     \
    const float4 b0_ = *(const float4*)&bl[kb_];                             \
    const float4 b1_ = *(const float4*)&bl[kb_ + 4];                         \
    const float bt_[8] = {b0_.x, b0_.y, b0_.z, b0_.w,                        \
                          b1_.x, b1_.y, b1_.z, b1_.w};                       \
    const f32x4 zz_ = {0, 0, 0, 0};                                          \
    f32x4 acc_[2][2];                                                        \
    acc_[0][0] = __builtin_amdgcn_mfma_f32_16x16x32_bf16(KA[0][1], qb[0][1], \
        __builtin_amdgcn_mfma_f32_16x16x32_bf16(KA[0][0], qb[0][0], zz_, 0, 0, 0), 0, 0, 0); \
    acc_[0][1] = __builtin_amdgcn_mfma_f32_16x16x32_bf16(KA[0][1], qb[1][1], \
        __builtin_amdgcn_mfma_f32_16x16x32_bf16(KA[0][0], qb[1][0], zz_, 0, 0, 0), 0, 0, 0); \
    acc_[1][0] = __builtin_amdgcn_mfma_f32_16x16x32_bf16(KA[1][1], qb[0][1], \
        __builtin_amdgcn_mfma_f32_16x16x32_bf16(KA[1][0], qb[0][0], zz_, 0, 0, 0), 0, 0, 0); \
    acc_[1][1] = __builtin_amdgcn_mfma_f32_16x16x32_bf16(KA[1][1], qb[1][1], \
        __builtin_amdgcn_mfma_f32_16x16x32_bf16(KA[1][0], qb[1][0], zz_, 0, 0, 0), 0, 0, 0); \
    const bool dm_ = (TILE) == nt - 1;                                       \
    _Pragma("unroll")                                                        \
    for (int ng_ = 0; ng_ < 2; ++ng_) {                                      \
        const int qr_ = qbase + (ng_ << 4) + n_l;                            \
        float pv_[8];                                                        \
        float la_ = 0.0f;                                                    \
        _Pragma("unroll")                                                    \
        for (int jj_ = 0; jj_ < 8; ++jj_) {                                  \
            float sv_ = fmaf(acc_[jj_ >> 2][ng_][jj_ & 3], KSC, bt_[jj_]);   \
            if (dm_) {                                                       \
                const int key_ = kb_ + jj_;                                  \
                if (!((key_ < qr_) || (qr_ == 0 && key_ == 0))) sv_ = -1.0e30f; \
            }                                                                \
            pv_[jj_] = __builtin_amdgcn_exp2f(sv_);                          \
            la_ += pv_[jj_];                                                 \
        }                                                                    \
        l[ng_] += la_;                                                       \
        union { unsigned u[4]; bf16x8 v; } pf_;                              \
        pf_.u[0] = pk2(pv_[0], pv_[1]);                                      \
        pf_.u[1] = pk2(pv_[2], pv_[3]);                                      \
        pf_.u[2] = pk2(pv_[4], pv_[5]);                                      \
        pf_.u[3] = pk2(pv_[6], pv_[7]);                                      \
        o[0][ng_] = __builtin_amdgcn_mfma_f32_16x16x32_bf16(VB[0], pf_.v, o[0][ng_], 0, 0, 0); \
        o[1][ng_] = __builtin_amdgcn_mfma_f32_16x16x32_bf16(VB[1], pf_.v, o[1][ng_], 0, 0, 0); \
        o[2][ng_] = __builtin_amdgcn_mfma_f32_16x16x32_bf16(VB[2], pf_.v, o[2][ng_], 0, 0, 0); \
        o[3][ng_] = __builtin_amdgcn_mfma_f32_16x16x32_bf16(VB[3], pf_.v, o[3][ng_], 0, 0, 0); \
    }                                                                        \
} while (0)

__global__ __launch_bounds__(512, 2)
void attn16(const float* __restrict__ Q, const float* __restrict__ beta,
            const unsigned short* __restrict__ F, float* __restrict__ out)
{
    __shared__ float slab[2][64][72];   // [kh][row][0..63: O, 64: l]
    __shared__ float bl[S_];            // exp-scaled beta (log2 domain)

    const int bid = blockIdx.x;
    const int hd = bid & 15;          // head pinned to XCD bid&7 (2 heads/XCD)
    const int pr = bid >> 4;          // pair index -> q-tiles (pr, 31-pr)

    const float* Qh = Q + (size_t)hd * S_ * D_;
    const unsigned short* Fh = F + (size_t)hd * 32 * 8192;

    const int t = threadIdx.x, lane = t & 63;
    const int wv = t >> 6;
    const int kh = wv & 1, par = (wv >> 1) & 1, qh = wv >> 2;
    const int n_l = lane & 15, qd = lane >> 4;

    // ---- stage beta*log2e in LDS once (broadcast reads thereafter) ----
    #pragma unroll
    for (int i = 0; i < 4; ++i) bl[t + i * 512] = beta[t + i * 512] * LOG2E;
    __syncthreads();

    // fragment offsets (ushort) within one tile's 8192-ushort block
    const int lo = lane * 8;
    int kfo[2][2], vfo[4];
    #pragma unroll
    for (int mb = 0; mb < 2; ++mb)
        #pragma unroll
        for (int hh = 0; hh < 2; ++hh)
            kfo[mb][hh] = ((kh << 2) | (mb << 1) | hh) * 512 + lo;
    #pragma unroll
    for (int mb = 0; mb < 4; ++mb)
        vfo[mb] = (8 + (kh << 2) + mb) * 512 + lo;

    const int kvo = (kh << 5) + (qd << 3);   // lane's key offset within a tile

    for (int p = 0; p < 2; ++p) {
        const int j = p ? (31 - pr) : pr;
        const int q0 = j << 6;
        const int nt = j + 1;
        const int qbase = q0 + (qh << 5);

        // ---- Qeff B-fragments from global fp32 Q (two q-rows per lane) ----
        bf16x8 qb[2][2];
        #pragma unroll
        for (int ng = 0; ng < 2; ++ng) {
            const int q = qbase + (ng << 4) + n_l;
            const float wp = (q > 0) ? 0.7f : 0.0f;
            const float wn = (q + 1 < S_) ? 0.7f : 0.0f;
            const float* qc = Qh + (size_t)q * D_;
            const float* qpp = qc - ((q > 0) ? D_ : 0);
            const float* qnn = qc + ((q + 1 < S_) ? D_ : 0);
            #pragma unroll
            for (int hh = 0; hh < 2; ++hh) {
                const int d0 = (hh << 5) + (qd << 3);
                float4 c0 = *(const float4*)(qc + d0),  c1 = *(const float4*)(qc + d0 + 4);
                float4 p0 = *(const float4*)(qpp + d0), p1 = *(const float4*)(qpp + d0 + 4);
                float4 n0 = *(const float4*)(qnn + d0), n1 = *(const float4*)(qnn + d0 + 4);
                float e0 = fmaf(wn, n0.x, fmaf(wp, p0.x, c0.x));
                float e1 = fmaf(wn, n0.y, fmaf(wp, p0.y, c0.y));
                float e2 = fmaf(wn, n0.z, fmaf(wp, p0.z, c0.z));
                float e3 = fmaf(wn, n0.w, fmaf(wp, p0.w, c0.w));
                float e4 = fmaf(wn, n1.x, fmaf(wp, p1.x, c1.x));
                float e5 = fmaf(wn, n1.y, fmaf(wp, p1.y, c1.y));
                float e6 = fmaf(wn, n1.z, fmaf(wp, p1.z, c1.z));
                float e7 = fmaf(wn, n1.w, fmaf(wp, p1.w, c1.w));
                union { unsigned u[4]; bf16x8 v; } qu;
                qu.u[0] = pk2(e0, e1); qu.u[1] = pk2(e2, e3);
                qu.u[2] = pk2(e4, e5); qu.u[3] = pk2(e6, e7);
                qb[ng][hh] = qu.v;
            }
        }

        f32x4 o[4][2];
        float l[2] = {0.0f, 0.0f};
        #pragma unroll
        for (int mb = 0; mb < 4; ++mb)
            #pragma unroll
            for (int ng = 0; ng < 2; ++ng) o[mb][ng] = (f32x4){0, 0, 0, 0};

        // ---- barrier-free K-loop over this wave's parity class, 2 buffers ----
        bf16x8 kaA[2][2], vbA[4];
        bf16x8 kaB[2][2], vbB[4];
        int it = par;
        if (it < nt) {
            LD_T(it, kaA, vbA);
            if (it + 2 < nt) LD_T(it + 2, kaB, vbB);
            while (it + 4 < nt) {
                COMP_T(it, kaA, vbA);
                LD_T(it + 4, kaA, vbA);
                COMP_T(it + 2, kaB, vbB);
                if (it + 6 < nt) LD_T(it + 6, kaB, vbB);
                it += 4;
            }
            COMP_T(it, kaA, vbA);
            if (it + 2 < nt) COMP_T(it + 2, kaB, vbB);
        }

        // ---- epilogue: quad-reduce l, 4-way (kh x par) combine, store ----
        #pragma unroll
        for (int ng = 0; ng < 2; ++ng) {
            l[ng] += __shfl_xor(l[ng], 16);
            l[ng] += __shfl_xor(l[ng], 32);
        }
        __syncthreads();   // protects previous pass's final reads
        if (par == 1) {
            #pragma unroll
            for (int ng = 0; ng < 2; ++ng) {
                const int row = (qh << 5) + (ng << 4) + n_l;
                #pragma unroll
                for (int mb = 0; mb < 4; ++mb)
                    *(float4*)&slab[kh][row][(mb << 4) + (qd << 2)] =
                        make_float4(o[mb][ng][0], o[mb][ng][1], o[mb][ng][2], o[mb][ng][3]);
                if (qd == 0) slab[kh][row][64] = l[ng];
            }
        }
        __syncthreads();
        if (par == 0) {
            #pragma unroll
            for (int ng = 0; ng < 2; ++ng) {
                const int row = (qh << 5) + (ng << 4) + n_l;
                #pragma unroll
                for (int mb = 0; mb < 4; ++mb) {
                    float4 pv4 = *(float4*)&slab[kh][row][(mb << 4) + (qd << 2)];
                    o[mb][ng][0] += pv4.x; o[mb][ng][1] += pv4.y;
                    o[mb][ng][2] += pv4.z; o[mb][ng][3] += pv4.w;
                }
                l[ng] += slab[kh][row][64];
                if (kh == 0) {   // publish kh0 totals (same wave read-then-write, in order)
                    #pragma unroll
                    for (int mb = 0; mb < 4; ++mb)
                        *(float4*)&slab[0][row][(mb << 4) + (qd << 2)] =
                            make_float4(o[mb][ng][0], o[mb][ng][1], o[mb][ng][2], o[mb][ng][3]);
                    if (qd == 0) slab[0][row][64] = l[ng];
                }
            }
        }
        __syncthreads();
        if (par == 0 && kh == 1) {
            #pragma unroll
            for (int ng = 0; ng < 2; ++ng) {
                const int row = (qh << 5) + (ng << 4) + n_l;
                const float inv = 1.0f / (l[ng] + slab[0][row][64]);
                float* op = out + ((size_t)hd * S_ + q0 + row) * D_ + (qd << 2);
                #pragma unroll
                for (int mb = 0; mb < 4; ++mb) {
                    float4 pv4 = *(float4*)&slab[0][row][(mb << 4) + (qd << 2)];
                    *(float4*)(op + (mb << 4)) =
                        make_float4((o[mb][ng][0] + pv4.x) * inv, (o[mb][ng][1] + pv4.y) * inv,
                                    (o[mb][ng][2] + pv4.z) * inv, (o[mb][ng][3] + pv4.w) * inv);
                }
            }
        }
    }
}

#undef LD_T
#undef COMP_T

extern "C" void kernel_launch(void* const* d_in, const int* in_sizes, int n_in,
                              void* d_out, int out_size, void* d_ws, size_t ws_size,
                              hipStream_t stream) {
    const float* Q    = (const float*)d_in[0];
    const float* K    = (const float*)d_in[1];
    const float* V    = (const float*)d_in[2];
    const float* beta = (const float*)d_in[3];
    // d_in[4]: causal mask (deterministic triu) — handled analytically in-kernel.
    float* out = (float*)d_out;

    unsigned short* F = (unsigned short*)d_ws;   // 16 hd x 32 t x 16 frag x 512 = 8 MB

    cvt8<<<dim3(512), 256, 0, stream>>>(K, V, F);
    attn16<<<dim3(256), 512, 0, stream>>>(Q, beta, F, out);
}